// Round 5
// baseline (297.748 us; speedup 1.0000x reference)
//
#include <hip/hip_runtime.h>
#include <stdint.h>

typedef __attribute__((ext_vector_type(8))) short bf16x8;   // 8 bf16 = 4 VGPRs
typedef __attribute__((ext_vector_type(4))) float f32x4;

#define DEVI __device__ __forceinline__

DEVI unsigned short f2bf(float f) {
    union { float f; uint32_t u; } v; v.f = f;
    uint32_t r = v.u + 0x7FFFu + ((v.u >> 16) & 1u);   // RNE
    return (unsigned short)(r >> 16);
}
DEVI float bf2f(unsigned short h) {
    union { uint32_t u; float f; } v; v.u = ((uint32_t)h) << 16;
    return v.f;
}
DEVI bf16x8 pack8(float4 a, float4 b) {
    bf16x8 o;
    o[0]=(short)f2bf(a.x); o[1]=(short)f2bf(a.y); o[2]=(short)f2bf(a.z); o[3]=(short)f2bf(a.w);
    o[4]=(short)f2bf(b.x); o[5]=(short)f2bf(b.y); o[6]=(short)f2bf(b.z); o[7]=(short)f2bf(b.w);
    return o;
}

#define GLOAD_LDS16(gsrc, ldst) \
    __builtin_amdgcn_global_load_lds((__attribute__((address_space(1))) void*)(gsrc), \
                                     (__attribute__((address_space(3))) void*)(ldst), 16, 0, 0)

// ---------------- prep: weight fp32->bf16 conversions + GRU weight assembly (es removed) -----
__global__ void k_prep(const float* __restrict__ U_w,
                       const float* __restrict__ W_w, const float* __restrict__ fc_w,
                       const float* __restrict__ hidden,
                       const float* __restrict__ Wih0, const float* __restrict__ Whh0,
                       const float* __restrict__ Wih1, const float* __restrict__ Whh1,
                       unsigned short* __restrict__ UW_BF,
                       unsigned short* __restrict__ WW_BF, unsigned short* __restrict__ FCW_BF,
                       unsigned short* __restrict__ A0, unsigned short* __restrict__ A1,
                       unsigned short* __restrict__ H1B,
                       unsigned short* __restrict__ B0, unsigned short* __restrict__ B1) {
    int i = blockIdx.x * blockDim.x + threadIdx.x;
    const int S0 = 262144, S1 = S0 + 131072, S2 = S1 + 16384;
    const int S3 = S2 + 32768, S4 = S3 + 1703936, S5 = S4 + 1048576;
    if (i < S0) {
        const float4* s = (const float4*)(U_w + (size_t)i * 8);
        *(bf16x8*)(UW_BF + (size_t)i * 8) = pack8(s[0], s[1]);
    } else if (i < S1) {
        int j = i - S0;
        const float4* s = (const float4*)(W_w + (size_t)j * 8);
        *(bf16x8*)(WW_BF + (size_t)j * 8) = pack8(s[0], s[1]);
    } else if (i < S2) {
        int j = i - S1;
        const float4* s = (const float4*)(fc_w + (size_t)j * 8);
        *(bf16x8*)(FCW_BF + (size_t)j * 8) = pack8(s[0], s[1]);
    } else if (i < S3) {
        int j = i - S2;
        int n = j >> 7, e0 = (j & 127) * 8;
        const float4* p0 = (const float4*)(hidden + (size_t)n * 1024 + e0);
        const float4* p1 = (const float4*)(hidden + 262144 + (size_t)n * 1024 + e0);
        bf16x8 o0 = pack8(p0[0], p0[1]);
        bf16x8 o1 = pack8(p1[0], p1[1]);
        *(bf16x8*)(A0 + (size_t)n * 3328 + 2304 + e0) = o0;
        *(bf16x8*)(A1 + (size_t)n * 2048 + 1024 + e0) = o1;
        *(bf16x8*)(H1B + (size_t)n * 1024 + e0) = o1;
    } else if (i < S4) {
        unsigned j = (unsigned)(i - S3);
        unsigned r = j / 416u;
        int kc = (int)(j - r * 416u) * 8;
        const float* src = nullptr;
        if (r < 2048)      src = (kc < 2304) ? (Wih0 + (size_t)r * 2304 + kc)
                                             : (Whh0 + (size_t)r * 1024 + (kc - 2304));
        else if (r < 3072) { if (kc < 2304)  src = Wih0 + (size_t)r * 2304 + kc; }
        else               { if (kc >= 2304) src = Whh0 + (size_t)(r - 1024) * 1024 + (kc - 2304); }
        bf16x8 o;
        if (src) { const float4* s4 = (const float4*)src; o = pack8(s4[0], s4[1]); }
        else     { for (int k = 0; k < 8; ++k) o[k] = 0; }
        *(bf16x8*)(B0 + (size_t)r * 3328 + kc) = o;
    } else if (i < S5) {
        int j = i - S4;
        int r = j >> 8;
        int kc = (j & 255) * 8;
        const float* src = nullptr;
        if (r < 2048)      src = (kc < 1024) ? (Wih1 + (size_t)r * 1024 + kc)
                                             : (Whh1 + (size_t)r * 1024 + (kc - 1024));
        else if (r < 3072) { if (kc < 1024)  src = Wih1 + (size_t)r * 1024 + kc; }
        else               { if (kc >= 1024) src = Whh1 + (size_t)(r - 1024) * 1024 + (kc - 1024); }
        bf16x8 o;
        if (src) { const float4* s4 = (const float4*)src; o = pack8(s4[0], s4[1]); }
        else     { for (int k = 0; k < 8; ++k) o[k] = 0; }
        *(bf16x8*)(B1 + (size_t)r * 2048 + kc) = o;
    }
}

// ---------------- split-K GEMM: Cpart[z] = A(MxK[slice z]) * B(NxK)^T ----------------
__global__ __launch_bounds__(256) void gemm_bt_sk(
        const unsigned short* __restrict__ A, const unsigned short* __restrict__ B,
        float* __restrict__ Cpart, int N, int K, int ksl) {
    __shared__ unsigned short sA[4096];
    __shared__ unsigned short sB[4096];
    const int nbx = gridDim.x;
    const int nwg = nbx * gridDim.y;
    int d = blockIdx.y * nbx + blockIdx.x;
    int f = d;
    if ((nwg & 7) == 0) { int cpx = nwg >> 3; f = (d & 7) * cpx + (d >> 3); }
    const int bx = f % nbx, by = f / nbx;
    const int z = blockIdx.z;
    const int t = threadIdx.x, wave = t >> 6, lane = t & 63;
    const int wm = wave >> 1, wn = wave & 1;
    const int lg = lane >> 4, r16 = lane & 15;
    const int row0 = by * 128, col0 = bx * 128;
    const int M = gridDim.y * 128;

    const int cr = t >> 2, ckc = (t & 3) * 8;
    const unsigned short* gA  = A + (size_t)(row0 + cr) * K + (size_t)z * ksl + ckc;
    const unsigned short* gA2 = gA + (size_t)64 * K;
    const unsigned short* gB  = B + (size_t)(col0 + cr) * K + (size_t)z * ksl + ckc;
    const unsigned short* gB2 = gB + (size_t)64 * K;
    unsigned short* lA1 = sA + wave * 512;
    unsigned short* lA2 = sA + 2048 + wave * 512;
    unsigned short* lB1 = sB + wave * 512;
    unsigned short* lB2 = sB + 2048 + wave * 512;

    f32x4 acc[4][4];
    #pragma unroll
    for (int i = 0; i < 4; ++i)
        #pragma unroll
        for (int j = 0; j < 4; ++j)
            #pragma unroll
            for (int q = 0; q < 4; ++q) acc[i][j][q] = 0.0f;

    const int ao = (wm * 64 + r16) * 32 + lg * 8;
    const int bo = (wn * 64 + r16) * 32 + lg * 8;

    #pragma unroll 1
    for (int kt = 0; kt < ksl; kt += 32) {
        GLOAD_LDS16(gA, lA1); GLOAD_LDS16(gA2, lA2);
        GLOAD_LDS16(gB, lB1); GLOAD_LDS16(gB2, lB2);
        gA += 32; gA2 += 32; gB += 32; gB2 += 32;
        __syncthreads();
        bf16x8 af[4], bfr[4];
        #pragma unroll
        for (int i = 0; i < 4; ++i) af[i]  = *(const bf16x8*)(sA + ao + i * 512);
        #pragma unroll
        for (int j = 0; j < 4; ++j) bfr[j] = *(const bf16x8*)(sB + bo + j * 512);
        #pragma unroll
        for (int i = 0; i < 4; ++i)
            #pragma unroll
            for (int j = 0; j < 4; ++j)
                acc[i][j] = __builtin_amdgcn_mfma_f32_16x16x32_bf16(af[i], bfr[j], acc[i][j], 0, 0, 0);
        __syncthreads();
    }
    float* Cz = Cpart + (size_t)z * (size_t)M * N;
    #pragma unroll
    for (int i = 0; i < 4; ++i)
        #pragma unroll
        for (int j = 0; j < 4; ++j)
            #pragma unroll
            for (int q = 0; q < 4; ++q) {
                int row = row0 + wm * 64 + i * 16 + lg * 4 + q;
                int col = col0 + wn * 64 + j * 16 + r16;
                Cz[(size_t)row * N + col] = acc[i][j][q];
            }
}

// ---------------- u-GEMM: 128x128 tile, B-in-registers, fp32-A reg-staging ----------------
// A = es fp32 (16384 x 2048); B = U_w bf16 (1024 x 2048). grid (8, 128), 256 thr, 4 waves.
// LDS: 2 x 16KB A-tiles only (32 KB -> 2 blocks/CU resident; cross-block overlap hides
// each block's serial LDS/MFMA phases). B-frags double-buffered in registers (L2-hot).
// One __syncthreads per K-tile; all waitcnts compiler-managed (T14 issue-early/use-late).
__global__ __launch_bounds__(256) void gemm_energy128(
        const float* __restrict__ Af32, const unsigned short* __restrict__ B,
        const float* __restrict__ attn_w, const float* __restrict__ U_b,
        const float* __restrict__ wbuf, float* __restrict__ e_part) {
    __shared__ __align__(16) char lds[32768];              // 2 x [128][64] bf16, XOR-swizzled

    const int t = threadIdx.x;
    const int w = t >> 6, lane = t & 63;
    const int wm = w >> 1, wn = w & 1;
    const int lg = lane >> 4, r16 = lane & 15;

    int d = blockIdx.y * gridDim.x + blockIdx.x;           // 1024 blocks
    int f = (d & 7) * 128 + (d >> 3);                      // bijective XCD swizzle (1024%8==0)
    const int bx = f & 7, by = f >> 3;                     // bx-minor: 8 bx-blocks of one by are
    const int row0 = by * 128, col0 = bx * 128;            // co-temporal on one XCD (A L2-reuse)

    const float* gA0 = Af32 + (size_t)row0 * 2048;
    const unsigned short* Bp = B + (size_t)(col0 + wn * 64 + r16) * 2048 + lg * 8;

    const unsigned swz = (unsigned)((r16 & 7) << 4);
    unsigned aoffm[4];
    #pragma unroll
    for (int m = 0; m < 4; ++m)
        aoffm[m] = (unsigned)((wm * 64 + m * 16 + r16) * 128 + lg * 16);

    float4 a_st[8];
    bf16x8 brA[8], brB[8];

    f32x4 acc[4][4];
    #pragma unroll
    for (int i = 0; i < 4; ++i)
        #pragma unroll
        for (int j = 0; j < 4; ++j)
            #pragma unroll
            for (int q = 0; q < 4; ++q) acc[i][j][q] = 0.0f;

#define ISSUE_A(T) do { \
    const float* gp_ = gA0 + (T) * 64; \
    _Pragma("unroll") \
    for (int j_ = 0; j_ < 8; ++j_) { \
        int c_ = t + j_ * 256; \
        a_st[j_] = *(const float4*)(gp_ + (size_t)(c_ >> 4) * 2048 + (c_ & 15) * 4); \
    } } while (0)

#define ISSUE_B(T, BR) do { \
    _Pragma("unroll") \
    for (int f8_ = 0; f8_ < 8; ++f8_) { \
        int n_ = f8_ & 3, kk_ = f8_ >> 2; \
        BR[f8_] = *(const bf16x8*)(Bp + (size_t)n_ * 32768 + (T) * 64 + kk_ * 32); \
    } } while (0)

#define CVT_WRITE(BUF) do { \
    _Pragma("unroll") \
    for (int j_ = 0; j_ < 8; ++j_) { \
        int c_ = t + j_ * 256; int row_ = c_ >> 4; \
        unsigned bo_ = ((unsigned)(row_ * 128 + (c_ & 15) * 8)) ^ ((unsigned)(row_ & 7) << 4); \
        uint2 pk_; \
        asm("v_cvt_pk_bf16_f32 %0, %1, %2" : "=v"(pk_.x) : "v"(a_st[j_].x), "v"(a_st[j_].y)); \
        asm("v_cvt_pk_bf16_f32 %0, %1, %2" : "=v"(pk_.y) : "v"(a_st[j_].z), "v"(a_st[j_].w)); \
        *(uint2*)(lds + (BUF) * 16384 + bo_) = pk_; \
    } } while (0)

#define COMPUTE(BUF, BR) do { \
    _Pragma("unroll") \
    for (int kk_ = 0; kk_ < 2; ++kk_) { \
        bf16x8 afr_[4]; \
        _Pragma("unroll") \
        for (int m_ = 0; m_ < 4; ++m_) \
            afr_[m_] = *(const bf16x8*)(lds + (BUF) * 16384 + ((aoffm[m_] + kk_ * 64) ^ swz)); \
        _Pragma("unroll") \
        for (int m_ = 0; m_ < 4; ++m_) \
            _Pragma("unroll") \
            for (int n_ = 0; n_ < 4; ++n_) \
                acc[m_][n_] = __builtin_amdgcn_mfma_f32_16x16x32_bf16( \
                    afr_[m_], BR[kk_ * 4 + n_], acc[m_][n_], 0, 0, 0); \
    } } while (0)

    // prologue: tile 0
    ISSUE_A(0);
    ISSUE_B(0, brA);
    CVT_WRITE(0);
    __syncthreads();

    #pragma unroll 1
    for (int tp = 0; tp < 16; ++tp) {
        int t0 = 2 * tp;
        // half 1: consume (lds0, brA) = tile t0; fill (lds1, brB) = t0+1
        ISSUE_A(t0 + 1);
        ISSUE_B(t0 + 1, brB);
        COMPUTE(0, brA);
        CVT_WRITE(1);
        __syncthreads();
        // half 2: consume (lds1, brB) = t0+1; fill (lds0, brA) = t0+2 (skip on last)
        bool more = (tp < 15);
        if (more) { ISSUE_A(t0 + 2); ISSUE_B(t0 + 2, brA); }
        COMPUTE(1, brB);
        if (more) { CVT_WRITE(0); }
        __syncthreads();
    }
#undef ISSUE_A
#undef ISSUE_B
#undef CVT_WRITE
#undef COMPUTE

    // fused energy epilogue: e_part[row*16 + bx*2 + wn]
    float aw[4], ub[4];
    #pragma unroll
    for (int n = 0; n < 4; ++n) {
        int col = col0 + wn * 64 + n * 16 + r16;
        aw[n] = attn_w[col];
        ub[n] = U_b[col];
    }
    #pragma unroll
    for (int m = 0; m < 4; ++m)
        #pragma unroll
        for (int q = 0; q < 4; ++q) {
            int lrow = wm * 64 + m * 16 + lg * 4 + q;
            int row = row0 + lrow;
            const float* wrow = wbuf + (size_t)(row & 255) * 1024;
            float e = 0.f;
            #pragma unroll
            for (int n = 0; n < 4; ++n) {
                int col = col0 + wn * 64 + n * 16 + r16;
                float cc = acc[m][n][q] + ub[n] + wrow[col];
                float ex = __expf(2.f * cc);               // tanh via exp
                e += aw[n] * (1.f - 2.f / (ex + 1.f));
            }
            e += __shfl_xor(e, 1); e += __shfl_xor(e, 2);
            e += __shfl_xor(e, 4); e += __shfl_xor(e, 8);
            if (r16 == 0) e_part[(size_t)row * 16 + bx * 2 + wn] = e;
        }
}

// ---------------- fused softmax + context + emb gather (fp32 es) ----------------
__global__ __launch_bounds__(256) void k_softctx(
        const float* __restrict__ es, const float* __restrict__ e_part,
        const float* __restrict__ emb, const int* __restrict__ x,
        float* __restrict__ attn_out, unsigned short* __restrict__ A0) {
    int n = blockIdx.x, t = threadIdx.x;
    __shared__ float as_[64];
    __shared__ float ev[64];
    {   // energy reduce: thread t -> s = t>>2, quarter (t&3)
        int s = t >> 2;
        const float* p = e_part + ((size_t)(s * 256 + n)) * 16 + (t & 3) * 4;
        float v = p[0] + p[1] + p[2] + p[3];
        v += __shfl_xor(v, 1); v += __shfl_xor(v, 2);
        if ((t & 3) == 0) ev[s] = v;
        __syncthreads();
        if (t < 64) {
            float e = ev[t];
            float mx = e;
            #pragma unroll
            for (int o = 1; o < 64; o <<= 1) mx = fmaxf(mx, __shfl_xor(mx, o));
            float ee = __expf(e - mx);
            float sum = ee;
            #pragma unroll
            for (int o = 1; o < 64; o <<= 1) sum += __shfl_xor(sum, o);
            float a = ee / sum;
            as_[t] = a;
            attn_out[t * 256 + n] = a;
        }
        __syncthreads();
    }
    float acc[8];
    #pragma unroll
    for (int k = 0; k < 8; ++k) acc[k] = 0.f;
    const float* base = es + (size_t)n * 2048 + t * 8;
    for (int s = 0; s < 64; ++s) {
        const float4* v4 = (const float4*)(base + (size_t)s * 524288);
        float4 v0 = v4[0], v1 = v4[1];
        float a = as_[s];
        acc[0] += a * v0.x; acc[1] += a * v0.y; acc[2] += a * v0.z; acc[3] += a * v0.w;
        acc[4] += a * v1.x; acc[5] += a * v1.y; acc[6] += a * v1.z; acc[7] += a * v1.w;
    }
    bf16x8 o;
    #pragma unroll
    for (int k = 0; k < 8; ++k) o[k] = (short)f2bf(acc[k]);
    *(bf16x8*)(A0 + (size_t)n * 3328 + t * 8) = o;
    if (t < 32) {
        const float4* e4 = (const float4*)(emb + (size_t)x[n] * 256 + t * 8);
        *(bf16x8*)(A0 + (size_t)n * 3328 + 2048 + t * 8) = pack8(e4[0], e4[1]);
    }
}

// GRU gate math; sums 4 split-K partials of g: [Z][256][4096] = [r | z | i_n | h_n]
__global__ void k_gru(const float* __restrict__ g, const float* __restrict__ b_ih,
                      const float* __restrict__ b_hh, const float* __restrict__ h_in,
                      float* __restrict__ h_out, unsigned short* __restrict__ a_dst,
                      int dst_pitch) {
    int i = blockIdx.x * blockDim.x + threadIdx.x;   // 262144
    int n = i >> 10, e = i & 1023;
    const float* gn = g + (size_t)n * 4096;
    float rr = 0.f, zz = 0.f, in_ = 0.f, hn_ = 0.f;
    #pragma unroll
    for (int z = 0; z < 4; ++z) {
        const float* gz = gn + (size_t)z * 1048576;
        rr  += gz[e];
        zz  += gz[1024 + e];
        in_ += gz[2048 + e];
        hn_ += gz[3072 + e];
    }
    rr  += b_ih[e]        + b_hh[e];
    zz  += b_ih[1024 + e] + b_hh[1024 + e];
    in_ += b_ih[2048 + e];
    hn_ += b_hh[2048 + e];
    float r = 1.f / (1.f + __expf(-rr));
    float z = 1.f / (1.f + __expf(-zz));
    float ex = __expf(2.f * (in_ + r * hn_));
    float nn = 1.f - 2.f / (ex + 1.f);
    float h = h_in[i];
    float ho = (1.f - z) * nn + z * h;
    h_out[i] = ho;
    a_dst[(size_t)n * dst_pitch + e] = f2bf(ho);
}

// sum 4 split-K partials + bias (w matrix: 256x1024)
__global__ void k_wsum(const float* __restrict__ Wp, const float* __restrict__ W_b,
                       float* __restrict__ Wout) {
    int i = blockIdx.x * blockDim.x + threadIdx.x;   // 262144
    Wout[i] = Wp[i] + Wp[262144 + i] + Wp[524288 + i] + Wp[786432 + i] + W_b[i & 1023];
}

// sum 4 split-K partials + bias (predictions: 256x128)
__global__ void k_fcsum(const float* __restrict__ Fp, const float* __restrict__ fc_b,
                        float* __restrict__ outp) {
    int i = blockIdx.x * blockDim.x + threadIdx.x;   // 32768
    outp[i] = Fp[i] + Fp[32768 + i] + Fp[65536 + i] + Fp[98304 + i] + fc_b[i & 127];
}

// ---------------- launch ----------------

extern "C" void kernel_launch(void* const* d_in, const int* in_sizes, int n_in,
                              void* d_out, int out_size, void* d_ws, size_t ws_size,
                              hipStream_t stream) {
    const int*   x      = (const int*)  d_in[0];
    const float* es     = (const float*)d_in[1];
    const float* hidden = (const float*)d_in[2];
    const float* emb    = (const float*)d_in[4];
    const float* U_w    = (const float*)d_in[5];
    const float* U_b    = (const float*)d_in[6];
    const float* W_w    = (const float*)d_in[7];
    const float* W_b    = (const float*)d_in[8];
    const float* attn_w = (const float*)d_in[9];
    const float* W_ih0  = (const float*)d_in[11];
    const float* W_hh0  = (const float*)d_in[12];
    const float* b_ih0  = (const float*)d_in[13];
    const float* b_hh0  = (const float*)d_in[14];
    const float* W_ih1  = (const float*)d_in[15];
    const float* W_hh1  = (const float*)d_in[16];
    const float* b_ih1  = (const float*)d_in[17];
    const float* b_hh1  = (const float*)d_in[18];
    const float* fc_w   = (const float*)d_in[19];
    const float* fc_b   = (const float*)d_in[20];

    float* out        = (float*)d_out;
    float* out_pred   = out;
    float* out_hidden = out + 32768;
    float* out_attn   = out + 32768 + 524288;

    char* ws = (char*)d_ws;
    size_t off = 0;
    auto alloc = [&](size_t bytes) { char* p = ws + off; off += (bytes + 255) & ~(size_t)255; return p; };
    unsigned short* UW_BF  = (unsigned short*)alloc((size_t)1024 * 2048 * 2);
    unsigned short* WW_BF  = (unsigned short*)alloc((size_t)1024 * 1024 * 2);
    unsigned short* FCW_BF = (unsigned short*)alloc((size_t)128 * 1024 * 2);
    unsigned short* H1_BF  = (unsigned short*)alloc((size_t)256 * 1024 * 2);
    unsigned short* B0     = (unsigned short*)alloc((size_t)4096 * 3328 * 2);
    unsigned short* B1     = (unsigned short*)alloc((size_t)4096 * 2048 * 2);
    unsigned short* A0     = (unsigned short*)alloc((size_t)256 * 3328 * 2);
    unsigned short* A1     = (unsigned short*)alloc((size_t)256 * 2048 * 2);
    unsigned short* FCA    = (unsigned short*)alloc((size_t)256 * 1024 * 2);
    float* WBUF  = (float*)alloc((size_t)256 * 1024 * 4);
    float* EPART = (float*)alloc((size_t)16384 * 16 * 4);
    float* WP    = (float*)alloc((size_t)4 * 256 * 1024 * 4);   // w partials; reused for fc partials
    float* G0P   = (float*)alloc((size_t)4 * 256 * 4096 * 4);   // GRU0 partials; reused for GRU1
    float* FCP   = WP;
    float* G1P   = G0P;

    // prep (weights only: 3,195,120 chunks of 8 elems)
    k_prep<<<12482, 256, 0, stream>>>(U_w, W_w, fc_w, hidden, W_ih0, W_hh0, W_ih1, W_hh1,
                                      UW_BF, WW_BF, FCW_BF, A0, A1, H1_BF, B0, B1);
    // w = hidden[1] @ W_w^T + W_b  (split-K 4)
    gemm_bt_sk<<<dim3(8, 2, 4), 256, 0, stream>>>(H1_BF, WW_BF, WP, 1024, 1024, 256);
    k_wsum<<<1024, 256, 0, stream>>>(WP, W_b, WBUF);
    // u-GEMM (fp32-A staging, B-in-regs) + fused energy epilogue
    gemm_energy128<<<dim3(8, 128), 256, 0, stream>>>(es, UW_BF, attn_w, U_b, WBUF, EPART);
    // softmax + context + embedding -> out_attn, A0
    k_softctx<<<256, 256, 0, stream>>>(es, EPART, emb, x, out_attn, A0);
    // GRU layer 0 (split-K 4: 3328 = 4*832)
    gemm_bt_sk<<<dim3(32, 2, 4), 256, 0, stream>>>(A0, B0, G0P, 4096, 3328, 832);
    k_gru<<<1024, 256, 0, stream>>>(G0P, b_ih0, b_hh0, hidden, out_hidden, A1, 2048);
    // GRU layer 1 (split-K 4: 2048 = 4*512)
    gemm_bt_sk<<<dim3(32, 2, 4), 256, 0, stream>>>(A1, B1, G1P, 4096, 2048, 512);
    k_gru<<<1024, 256, 0, stream>>>(G1P, b_ih1, b_hh1, hidden + 262144, out_hidden + 262144, FCA, 1024);
    // predictions = h1 @ fc_w^T + fc_b (split-K 4)
    gemm_bt_sk<<<dim3(1, 2, 4), 256, 0, stream>>>(FCA, FCW_BF, FCP, 128, 1024, 256);
    k_fcsum<<<128, 256, 0, stream>>>(FCP, fc_b, out_pred);
}

// Round 6
// 222.847 us; speedup vs baseline: 1.3361x; 1.3361x over previous
//
#include <hip/hip_runtime.h>
#include <stdint.h>

typedef __attribute__((ext_vector_type(8))) short bf16x8;   // 8 bf16 = 4 VGPRs
typedef __attribute__((ext_vector_type(4))) float f32x4;

#define DEVI __device__ __forceinline__

DEVI unsigned short f2bf(float f) {
    union { float f; uint32_t u; } v; v.f = f;
    uint32_t r = v.u + 0x7FFFu + ((v.u >> 16) & 1u);   // RNE
    return (unsigned short)(r >> 16);
}
DEVI float bf2f(unsigned short h) {
    union { uint32_t u; float f; } v; v.u = ((uint32_t)h) << 16;
    return v.f;
}
DEVI bf16x8 pack8(float4 a, float4 b) {
    bf16x8 o;
    o[0]=(short)f2bf(a.x); o[1]=(short)f2bf(a.y); o[2]=(short)f2bf(a.z); o[3]=(short)f2bf(a.w);
    o[4]=(short)f2bf(b.x); o[5]=(short)f2bf(b.y); o[6]=(short)f2bf(b.z); o[7]=(short)f2bf(b.w);
    return o;
}

#define GLOAD_LDS16(gsrc, ldst) \
    __builtin_amdgcn_global_load_lds((__attribute__((address_space(1))) void*)(gsrc), \
                                     (__attribute__((address_space(3))) void*)(ldst), 16, 0, 0)

#define BARR asm volatile("s_barrier" ::: "memory")
#define WAITV(n) asm volatile("s_waitcnt vmcnt(" #n ")" ::: "memory")
#define LGKM0 do { asm volatile("s_waitcnt lgkmcnt(0)" ::: "memory"); \
                   __builtin_amdgcn_sched_barrier(0); } while (0)

// ---------------- fused prep: all fp32->bf16 conversions + GRU weight assembly ----------------
__global__ void k_prep(const float* __restrict__ es, const float* __restrict__ U_w,
                       const float* __restrict__ W_w, const float* __restrict__ fc_w,
                       const float* __restrict__ hidden,
                       const float* __restrict__ Wih0, const float* __restrict__ Whh0,
                       const float* __restrict__ Wih1, const float* __restrict__ Whh1,
                       unsigned short* __restrict__ ES_BF, unsigned short* __restrict__ UW_BF,
                       unsigned short* __restrict__ WW_BF, unsigned short* __restrict__ FCW_BF,
                       unsigned short* __restrict__ A0, unsigned short* __restrict__ A1,
                       unsigned short* __restrict__ H1B,
                       unsigned short* __restrict__ B0, unsigned short* __restrict__ B1) {
    int i = blockIdx.x * blockDim.x + threadIdx.x;
    const int S0 = 4194304, S1 = S0 + 262144, S2 = S1 + 131072, S3 = S2 + 16384;
    const int S4 = S3 + 32768, S5 = S4 + 1703936, S6 = S5 + 1048576;
    if (i < S0) {
        const float4* s = (const float4*)(es + (size_t)i * 8);
        *(bf16x8*)(ES_BF + (size_t)i * 8) = pack8(s[0], s[1]);
    } else if (i < S1) {
        int j = i - S0;
        const float4* s = (const float4*)(U_w + (size_t)j * 8);
        *(bf16x8*)(UW_BF + (size_t)j * 8) = pack8(s[0], s[1]);
    } else if (i < S2) {
        int j = i - S1;
        const float4* s = (const float4*)(W_w + (size_t)j * 8);
        *(bf16x8*)(WW_BF + (size_t)j * 8) = pack8(s[0], s[1]);
    } else if (i < S3) {
        int j = i - S2;
        const float4* s = (const float4*)(fc_w + (size_t)j * 8);
        *(bf16x8*)(FCW_BF + (size_t)j * 8) = pack8(s[0], s[1]);
    } else if (i < S4) {
        int j = i - S3;
        int n = j >> 7, e0 = (j & 127) * 8;
        const float4* p0 = (const float4*)(hidden + (size_t)n * 1024 + e0);
        const float4* p1 = (const float4*)(hidden + 262144 + (size_t)n * 1024 + e0);
        bf16x8 o0 = pack8(p0[0], p0[1]);
        bf16x8 o1 = pack8(p1[0], p1[1]);
        *(bf16x8*)(A0 + (size_t)n * 3328 + 2304 + e0) = o0;
        *(bf16x8*)(A1 + (size_t)n * 2048 + 1024 + e0) = o1;
        *(bf16x8*)(H1B + (size_t)n * 1024 + e0) = o1;
    } else if (i < S5) {
        unsigned j = (unsigned)(i - S4);
        unsigned r = j / 416u;
        int kc = (int)(j - r * 416u) * 8;
        const float* src = nullptr;
        if (r < 2048)      src = (kc < 2304) ? (Wih0 + (size_t)r * 2304 + kc)
                                             : (Whh0 + (size_t)r * 1024 + (kc - 2304));
        else if (r < 3072) { if (kc < 2304)  src = Wih0 + (size_t)r * 2304 + kc; }
        else               { if (kc >= 2304) src = Whh0 + (size_t)(r - 1024) * 1024 + (kc - 2304); }
        bf16x8 o;
        if (src) { const float4* s4 = (const float4*)src; o = pack8(s4[0], s4[1]); }
        else     { for (int k = 0; k < 8; ++k) o[k] = 0; }
        *(bf16x8*)(B0 + (size_t)r * 3328 + kc) = o;
    } else if (i < S6) {
        int j = i - S5;
        int r = j >> 8;
        int kc = (j & 255) * 8;
        const float* src = nullptr;
        if (r < 2048)      src = (kc < 1024) ? (Wih1 + (size_t)r * 1024 + kc)
                                             : (Whh1 + (size_t)r * 1024 + (kc - 1024));
        else if (r < 3072) { if (kc < 1024)  src = Wih1 + (size_t)r * 1024 + kc; }
        else               { if (kc >= 1024) src = Whh1 + (size_t)(r - 1024) * 1024 + (kc - 1024); }
        bf16x8 o;
        if (src) { const float4* s4 = (const float4*)src; o = pack8(s4[0], s4[1]); }
        else     { for (int k = 0; k < 8; ++k) o[k] = 0; }
        *(bf16x8*)(B1 + (size_t)r * 2048 + kc) = o;
    }
}

// ---------------- split-K GEMM: Cpart[z] = A(MxK[slice z]) * B(NxK)^T ----------------
__global__ __launch_bounds__(256) void gemm_bt_sk(
        const unsigned short* __restrict__ A, const unsigned short* __restrict__ B,
        float* __restrict__ Cpart, int N, int K, int ksl) {
    __shared__ unsigned short sA[4096];
    __shared__ unsigned short sB[4096];
    const int nbx = gridDim.x;
    const int nwg = nbx * gridDim.y;
    int d = blockIdx.y * nbx + blockIdx.x;
    int f = d;
    if ((nwg & 7) == 0) { int cpx = nwg >> 3; f = (d & 7) * cpx + (d >> 3); }
    const int bx = f % nbx, by = f / nbx;
    const int z = blockIdx.z;
    const int t = threadIdx.x, wave = t >> 6, lane = t & 63;
    const int wm = wave >> 1, wn = wave & 1;
    const int lg = lane >> 4, r16 = lane & 15;
    const int row0 = by * 128, col0 = bx * 128;
    const int M = gridDim.y * 128;

    const int cr = t >> 2, ckc = (t & 3) * 8;
    const unsigned short* gA  = A + (size_t)(row0 + cr) * K + (size_t)z * ksl + ckc;
    const unsigned short* gA2 = gA + (size_t)64 * K;
    const unsigned short* gB  = B + (size_t)(col0 + cr) * K + (size_t)z * ksl + ckc;
    const unsigned short* gB2 = gB + (size_t)64 * K;
    unsigned short* lA1 = sA + wave * 512;
    unsigned short* lA2 = sA + 2048 + wave * 512;
    unsigned short* lB1 = sB + wave * 512;
    unsigned short* lB2 = sB + 2048 + wave * 512;

    f32x4 acc[4][4];
    #pragma unroll
    for (int i = 0; i < 4; ++i)
        #pragma unroll
        for (int j = 0; j < 4; ++j)
            #pragma unroll
            for (int q = 0; q < 4; ++q) acc[i][j][q] = 0.0f;

    const int ao = (wm * 64 + r16) * 32 + lg * 8;
    const int bo = (wn * 64 + r16) * 32 + lg * 8;

    #pragma unroll 1
    for (int kt = 0; kt < ksl; kt += 32) {
        GLOAD_LDS16(gA, lA1); GLOAD_LDS16(gA2, lA2);
        GLOAD_LDS16(gB, lB1); GLOAD_LDS16(gB2, lB2);
        gA += 32; gA2 += 32; gB += 32; gB2 += 32;
        __syncthreads();
        bf16x8 af[4], bfr[4];
        #pragma unroll
        for (int i = 0; i < 4; ++i) af[i]  = *(const bf16x8*)(sA + ao + i * 512);
        #pragma unroll
        for (int j = 0; j < 4; ++j) bfr[j] = *(const bf16x8*)(sB + bo + j * 512);
        #pragma unroll
        for (int i = 0; i < 4; ++i)
            #pragma unroll
            for (int j = 0; j < 4; ++j)
                acc[i][j] = __builtin_amdgcn_mfma_f32_16x16x32_bf16(af[i], bfr[j], acc[i][j], 0, 0, 0);
        __syncthreads();
    }
    float* Cz = Cpart + (size_t)z * (size_t)M * N;
    #pragma unroll
    for (int i = 0; i < 4; ++i)
        #pragma unroll
        for (int j = 0; j < 4; ++j)
            #pragma unroll
            for (int q = 0; q < 4; ++q) {
                int row = row0 + wm * 64 + i * 16 + lg * 4 + q;
                int col = col0 + wn * 64 + j * 16 + r16;
                Cz[(size_t)row * N + col] = acc[i][j][q];
            }
}

// ---------------- 256^2 u-GEMM, BK=32, 4-slot LDS ring, counted never-drain vmcnt ----------
// A = es_bf16 (16384 x 2048); B = U_w_bf16 (1024 x 2048). grid (4, 64), 512 thr, 8 waves.
// Ring: 4 slots x (A 256x32 + B 256x32) bf16 = 4 x 32 KiB = 128 KiB.
// Per tile t: STAGE(t+3) [4 gload_lds/thread] -> vmcnt(12) [waits tile t ONLY; tiles
// t+1..t+3 = 12 loads stay in flight, ~3 tiles of MFMA cover >> 900cy HBM latency]
// -> barrier -> 2 phases x {ds_read, lgkmcnt(0)+sched_barrier, setprio, 16 MFMA} -> barrier.
// Swizzle: logical (r,k) at byte (r*64+k*16)^((r&7)<<4); exact inverse baked into the
// per-lane gload SOURCE (rule #21: linear LDS dest + inverse-permuted source + swz read).
__global__ __launch_bounds__(512) void gemm_energy256(
        const unsigned short* __restrict__ A, const unsigned short* __restrict__ B,
        const float* __restrict__ attn_w, const float* __restrict__ U_b,
        const float* __restrict__ wbuf, float* __restrict__ e_part) {
    const int NT = 64;                                     // 2048 / 32
    __shared__ __align__(16) char lds[131072];

    const int t = threadIdx.x;
    const int w = t >> 6, lane = t & 63;
    const int wm = w >> 2, wn = w & 3;
    const int lg = lane >> 4, r16 = lane & 15;

    int d = blockIdx.y * gridDim.x + blockIdx.x;           // 256 blocks
    int f = (d & 7) * 32 + (d >> 3);                       // bijective XCD swizzle
    const int bx = f & 3, by = f >> 2;
    const int row0 = by * 256, col0 = bx * 256;

    // staging: thread covers 4 chunks (q): q<2 -> A region, q>=2 -> B region.
    // stored slot s in matrix region; slot s=(rho,kap) holds logical (r,k):
    //   bit0 = (rho ^ rho>>2) & 1;  r = (rho & ~1) | bit0;  k = kap ^ ((rho&2)|bit0)
    const unsigned short* gsrc[4];
    unsigned lodst[4];
    #pragma unroll
    for (int q = 0; q < 4; ++q) {
        int isB = q >> 1;
        int s = (q & 1) * 512 + w * 64 + lane;
        int rho = s >> 2, kap = s & 3;
        int bit0 = (rho ^ (rho >> 2)) & 1;
        int r = (rho & ~1) | bit0;
        int k = kap ^ ((rho & 2) | bit0);
        gsrc[q] = (isB ? B + (size_t)(col0 + r) * 2048
                       : A + (size_t)(row0 + r) * 2048) + k * 8;
        lodst[q] = (unsigned)(isB * 16384 + ((q & 1) * 512 + w * 64) * 16);
    }

#define STAGE(T) do { \
    unsigned rb_ = (unsigned)(((T) & 3) * 32768); \
    _Pragma("unroll") \
    for (int q_ = 0; q_ < 4; ++q_) \
        GLOAD_LDS16(gsrc[q_] + (size_t)(T) * 32, lds + rb_ + lodst[q_]); \
} while (0)

    // read offsets: A rows wm*128+m*16+r16 (m 0..7), B rows wn*64+n*16+r16, kslot lg
    const unsigned swz3 = (unsigned)((r16 & 7) << 4);
    unsigned aoff[8], boff[4];
    #pragma unroll
    for (int m = 0; m < 8; ++m)
        aoff[m] = ((unsigned)((wm * 128 + m * 16 + r16) * 64 + lg * 16)) ^ swz3;
    #pragma unroll
    for (int n = 0; n < 4; ++n)
        boff[n] = 16384u + (((unsigned)((wn * 64 + n * 16 + r16) * 64 + lg * 16)) ^ swz3);

    f32x4 acc[8][4];
    #pragma unroll
    for (int m = 0; m < 8; ++m)
        #pragma unroll
        for (int n = 0; n < 4; ++n)
            #pragma unroll
            for (int q = 0; q < 4; ++q) acc[m][n][q] = 0.0f;

    // prologue: 3 tiles in flight
    STAGE(0); STAGE(1); STAGE(2);

    #pragma unroll 1
    for (int tt = 0; tt < NT; ++tt) {
        if (tt < NT - 3)       { STAGE(tt + 3); WAITV(12); }   // steady: wait tile tt only
        else if (tt == NT - 3) { WAITV(8); }
        else if (tt == NT - 2) { WAITV(4); }
        else                   { WAITV(0); }
        BARR;
        const char* lp = (const char*)lds + (tt & 3) * 32768;
        bf16x8 bfr[4], afr[4];
        #pragma unroll
        for (int n = 0; n < 4; ++n) bfr[n] = *(const bf16x8*)(lp + boff[n]);
        #pragma unroll
        for (int m = 0; m < 4; ++m) afr[m] = *(const bf16x8*)(lp + aoff[m]);
        LGKM0;
        __builtin_amdgcn_s_setprio(1);
        #pragma unroll
        for (int m = 0; m < 4; ++m)
            #pragma unroll
            for (int n = 0; n < 4; ++n)
                acc[m][n] = __builtin_amdgcn_mfma_f32_16x16x32_bf16(
                    afr[m], bfr[n], acc[m][n], 0, 0, 0);
        __builtin_amdgcn_s_setprio(0);
        #pragma unroll
        for (int m = 0; m < 4; ++m) afr[m] = *(const bf16x8*)(lp + aoff[4 + m]);
        LGKM0;
        __builtin_amdgcn_s_setprio(1);
        #pragma unroll
        for (int m = 0; m < 4; ++m)
            #pragma unroll
            for (int n = 0; n < 4; ++n)
                acc[4 + m][n] = __builtin_amdgcn_mfma_f32_16x16x32_bf16(
                    afr[m], bfr[n], acc[4 + m][n], 0, 0, 0);
        __builtin_amdgcn_s_setprio(0);
        BARR;   // all waves done reading slot tt&3 before iteration tt+1 stages tile tt+4
    }
#undef STAGE

    // fused energy epilogue: e_part[row*16 + bx*4 + wn]
    float aw[4], ub[4];
    #pragma unroll
    for (int n = 0; n < 4; ++n) {
        int col = col0 + wn * 64 + n * 16 + r16;
        aw[n] = attn_w[col];
        ub[n] = U_b[col];
    }
    #pragma unroll
    for (int m = 0; m < 8; ++m)
        #pragma unroll
        for (int q = 0; q < 4; ++q) {
            int lrow = wm * 128 + m * 16 + lg * 4 + q;     // local row = batch index
            const float* wrow = wbuf + (size_t)lrow * 1024;
            float e = 0.f;
            #pragma unroll
            for (int n = 0; n < 4; ++n) {
                int col = col0 + wn * 64 + n * 16 + r16;
                float cc = acc[m][n][q] + ub[n] + wrow[col];
                float ex = __expf(2.f * cc);               // tanh via exp
                e += aw[n] * (1.f - 2.f / (ex + 1.f));
            }
            e += __shfl_xor(e, 1); e += __shfl_xor(e, 2);
            e += __shfl_xor(e, 4); e += __shfl_xor(e, 8);
            if (r16 == 0) e_part[(size_t)(row0 + lrow) * 16 + bx * 4 + wn] = e;
        }
}

// ---------------- fused softmax + context + emb gather (bf16 es) ----------------
__global__ __launch_bounds__(256) void k_softctx(
        const unsigned short* __restrict__ esb, const float* __restrict__ e_part,
        const float* __restrict__ emb, const int* __restrict__ x,
        float* __restrict__ attn_out, unsigned short* __restrict__ A0) {
    int n = blockIdx.x, t = threadIdx.x;
    __shared__ float as_[64];
    __shared__ float ev[64];
    {   // energy reduce: thread t -> s = t>>2, quarter (t&3)
        int s = t >> 2;
        const float* p = e_part + ((size_t)(s * 256 + n)) * 16 + (t & 3) * 4;
        float v = p[0] + p[1] + p[2] + p[3];
        v += __shfl_xor(v, 1); v += __shfl_xor(v, 2);
        if ((t & 3) == 0) ev[s] = v;
        __syncthreads();
        if (t < 64) {
            float e = ev[t];
            float mx = e;
            #pragma unroll
            for (int o = 1; o < 64; o <<= 1) mx = fmaxf(mx, __shfl_xor(mx, o));
            float ee = __expf(e - mx);
            float sum = ee;
            #pragma unroll
            for (int o = 1; o < 64; o <<= 1) sum += __shfl_xor(sum, o);
            float a = ee / sum;
            as_[t] = a;
            attn_out[t * 256 + n] = a;
        }
        __syncthreads();
    }
    float acc[8];
    #pragma unroll
    for (int k = 0; k < 8; ++k) acc[k] = 0.f;
    const unsigned short* base = esb + (size_t)n * 2048 + t * 8;
    for (int s = 0; s < 64; ++s) {
        bf16x8 v = *(const bf16x8*)(base + (size_t)s * 524288);
        float a = as_[s];
        #pragma unroll
        for (int k = 0; k < 8; ++k) acc[k] += a * bf2f((unsigned short)v[k]);
    }
    bf16x8 o;
    #pragma unroll
    for (int k = 0; k < 8; ++k) o[k] = (short)f2bf(acc[k]);
    *(bf16x8*)(A0 + (size_t)n * 3328 + t * 8) = o;
    if (t < 32) {
        const float4* e4 = (const float4*)(emb + (size_t)x[n] * 256 + t * 8);
        *(bf16x8*)(A0 + (size_t)n * 3328 + 2048 + t * 8) = pack8(e4[0], e4[1]);
    }
}

// GRU gate math; sums 4 split-K partials of g: [Z][256][4096] = [r | z | i_n | h_n]
__global__ void k_gru(const float* __restrict__ g, const float* __restrict__ b_ih,
                      const float* __restrict__ b_hh, const float* __restrict__ h_in,
                      float* __restrict__ h_out, unsigned short* __restrict__ a_dst,
                      int dst_pitch) {
    int i = blockIdx.x * blockDim.x + threadIdx.x;   // 262144
    int n = i >> 10, e = i & 1023;
    const float* gn = g + (size_t)n * 4096;
    float rr = 0.f, zz = 0.f, in_ = 0.f, hn_ = 0.f;
    #pragma unroll
    for (int z = 0; z < 4; ++z) {
        const float* gz = gn + (size_t)z * 1048576;
        rr  += gz[e];
        zz  += gz[1024 + e];
        in_ += gz[2048 + e];
        hn_ += gz[3072 + e];
    }
    rr  += b_ih[e]        + b_hh[e];
    zz  += b_ih[1024 + e] + b_hh[1024 + e];
    in_ += b_ih[2048 + e];
    hn_ += b_hh[2048 + e];
    float r = 1.f / (1.f + __expf(-rr));
    float z = 1.f / (1.f + __expf(-zz));
    float ex = __expf(2.f * (in_ + r * hn_));
    float nn = 1.f - 2.f / (ex + 1.f);
    float h = h_in[i];
    float ho = (1.f - z) * nn + z * h;
    h_out[i] = ho;
    a_dst[(size_t)n * dst_pitch + e] = f2bf(ho);
}

// sum 4 split-K partials + bias (w matrix: 256x1024)
__global__ void k_wsum(const float* __restrict__ Wp, const float* __restrict__ W_b,
                       float* __restrict__ Wout) {
    int i = blockIdx.x * blockDim.x + threadIdx.x;   // 262144
    Wout[i] = Wp[i] + Wp[262144 + i] + Wp[524288 + i] + Wp[786432 + i] + W_b[i & 1023];
}

// sum 4 split-K partials + bias (predictions: 256x128)
__global__ void k_fcsum(const float* __restrict__ Fp, const float* __restrict__ fc_b,
                        float* __restrict__ outp) {
    int i = blockIdx.x * blockDim.x + threadIdx.x;   // 32768
    outp[i] = Fp[i] + Fp[32768 + i] + Fp[65536 + i] + Fp[98304 + i] + fc_b[i & 127];
}

// ---------------- launch ----------------

extern "C" void kernel_launch(void* const* d_in, const int* in_sizes, int n_in,
                              void* d_out, int out_size, void* d_ws, size_t ws_size,
                              hipStream_t stream) {
    const int*   x      = (const int*)  d_in[0];
    const float* es     = (const float*)d_in[1];
    const float* hidden = (const float*)d_in[2];
    const float* emb    = (const float*)d_in[4];
    const float* U_w    = (const float*)d_in[5];
    const float* U_b    = (const float*)d_in[6];
    const float* W_w    = (const float*)d_in[7];
    const float* W_b    = (const float*)d_in[8];
    const float* attn_w = (const float*)d_in[9];
    const float* W_ih0  = (const float*)d_in[11];
    const float* W_hh0  = (const float*)d_in[12];
    const float* b_ih0  = (const float*)d_in[13];
    const float* b_hh0  = (const float*)d_in[14];
    const float* W_ih1  = (const float*)d_in[15];
    const float* W_hh1  = (const float*)d_in[16];
    const float* b_ih1  = (const float*)d_in[17];
    const float* b_hh1  = (const float*)d_in[18];
    const float* fc_w   = (const float*)d_in[19];
    const float* fc_b   = (const float*)d_in[20];

    float* out        = (float*)d_out;
    float* out_pred   = out;
    float* out_hidden = out + 32768;
    float* out_attn   = out + 32768 + 524288;

    char* ws = (char*)d_ws;
    size_t off = 0;
    auto alloc = [&](size_t bytes) { char* p = ws + off; off += (bytes + 255) & ~(size_t)255; return p; };
    unsigned short* ES_BF  = (unsigned short*)alloc((size_t)16384 * 2048 * 2);
    unsigned short* UW_BF  = (unsigned short*)alloc((size_t)1024 * 2048 * 2);
    unsigned short* WW_BF  = (unsigned short*)alloc((size_t)1024 * 1024 * 2);
    unsigned short* FCW_BF = (unsigned short*)alloc((size_t)128 * 1024 * 2);
    unsigned short* H1_BF  = (unsigned short*)alloc((size_t)256 * 1024 * 2);
    unsigned short* B0     = (unsigned short*)alloc((size_t)4096 * 3328 * 2);
    unsigned short* B1     = (unsigned short*)alloc((size_t)4096 * 2048 * 2);
    unsigned short* A0     = (unsigned short*)alloc((size_t)256 * 3328 * 2);
    unsigned short* A1     = (unsigned short*)alloc((size_t)256 * 2048 * 2);
    unsigned short* FCA    = (unsigned short*)alloc((size_t)256 * 1024 * 2);
    float* WBUF  = (float*)alloc((size_t)256 * 1024 * 4);
    float* EPART = (float*)alloc((size_t)16384 * 16 * 4);
    float* WP    = (float*)alloc((size_t)4 * 256 * 1024 * 4);   // w partials; reused for fc partials
    float* G0P   = (float*)alloc((size_t)4 * 256 * 4096 * 4);   // GRU0 partials; reused for GRU1
    float* FCP   = WP;
    float* G1P   = G0P;

    // fused prep
    k_prep<<<28864, 256, 0, stream>>>(es, U_w, W_w, fc_w, hidden, W_ih0, W_hh0, W_ih1, W_hh1,
                                      ES_BF, UW_BF, WW_BF, FCW_BF, A0, A1, H1_BF, B0, B1);
    // w = hidden[1] @ W_w^T + W_b  (split-K 4)
    gemm_bt_sk<<<dim3(8, 2, 4), 256, 0, stream>>>(H1_BF, WW_BF, WP, 1024, 1024, 256);
    k_wsum<<<1024, 256, 0, stream>>>(WP, W_b, WBUF);
    // u-GEMM + fused energy epilogue (4-deep ring, counted vmcnt)
    gemm_energy256<<<dim3(4, 64), 512, 0, stream>>>(ES_BF, UW_BF, attn_w, U_b, WBUF, EPART);
    // softmax + context + embedding -> out_attn, A0
    k_softctx<<<256, 256, 0, stream>>>(ES_BF, EPART, emb, x, out_attn, A0);
    // GRU layer 0 (split-K 4: 3328 = 4*832)
    gemm_bt_sk<<<dim3(32, 2, 4), 256, 0, stream>>>(A0, B0, G0P, 4096, 3328, 832);
    k_gru<<<1024, 256, 0, stream>>>(G0P, b_ih0, b_hh0, hidden, out_hidden, A1, 2048);
    // GRU layer 1 (split-K 4: 2048 = 4*512)
    gemm_bt_sk<<<dim3(32, 2, 4), 256, 0, stream>>>(A1, B1, G1P, 4096, 2048, 512);
    k_gru<<<1024, 256, 0, stream>>>(G1P, b_ih1, b_hh1, hidden + 262144, out_hidden + 262144, FCA, 1024);
    // predictions = h1 @ fc_w^T + fc_b (split-K 4)
    gemm_bt_sk<<<dim3(1, 2, 4), 256, 0, stream>>>(FCA, FCW_BF, FCP, 128, 1024, 256);
    k_fcsum<<<128, 256, 0, stream>>>(FCP, fc_b, out_pred);
}

// Round 8
// 219.718 us; speedup vs baseline: 1.3551x; 1.0142x over previous
//
#include <hip/hip_runtime.h>
#include <stdint.h>

typedef __attribute__((ext_vector_type(8))) short bf16x8;   // 8 bf16 = 4 VGPRs
typedef __attribute__((ext_vector_type(4))) float f32x4;

#define DEVI __device__ __forceinline__

DEVI unsigned short f2bf(float f) {
    union { float f; uint32_t u; } v; v.f = f;
    uint32_t r = v.u + 0x7FFFu + ((v.u >> 16) & 1u);   // RNE
    return (unsigned short)(r >> 16);
}
DEVI float bf2f(unsigned short h) {
    union { uint32_t u; float f; } v; v.u = ((uint32_t)h) << 16;
    return v.f;
}
DEVI bf16x8 pack8(float4 a, float4 b) {
    bf16x8 o;
    o[0]=(short)f2bf(a.x); o[1]=(short)f2bf(a.y); o[2]=(short)f2bf(a.z); o[3]=(short)f2bf(a.w);
    o[4]=(short)f2bf(b.x); o[5]=(short)f2bf(b.y); o[6]=(short)f2bf(b.z); o[7]=(short)f2bf(b.w);
    return o;
}

#define GLOAD_LDS16(gsrc, ldst) \
    __builtin_amdgcn_global_load_lds((__attribute__((address_space(1))) void*)(gsrc), \
                                     (__attribute__((address_space(3))) void*)(ldst), 16, 0, 0)

#define BARR asm volatile("s_barrier" ::: "memory")
#define WAITV(n) asm volatile("s_waitcnt vmcnt(" #n ")" ::: "memory")

// ---------------- fused prep: all fp32->bf16 conversions + GRU weight assembly ----------------
__global__ void k_prep(const float* __restrict__ es, const float* __restrict__ U_w,
                       const float* __restrict__ W_w, const float* __restrict__ fc_w,
                       const float* __restrict__ hidden,
                       const float* __restrict__ Wih0, const float* __restrict__ Whh0,
                       const float* __restrict__ Wih1, const float* __restrict__ Whh1,
                       unsigned short* __restrict__ ES_BF, unsigned short* __restrict__ UW_BF,
                       unsigned short* __restrict__ WW_BF, unsigned short* __restrict__ FCW_BF,
                       unsigned short* __restrict__ A0, unsigned short* __restrict__ A1,
                       unsigned short* __restrict__ H1B,
                       unsigned short* __restrict__ B0, unsigned short* __restrict__ B1) {
    int i = blockIdx.x * blockDim.x + threadIdx.x;
    const int S0 = 4194304, S1 = S0 + 262144, S2 = S1 + 131072, S3 = S2 + 16384;
    const int S4 = S3 + 32768, S5 = S4 + 1703936, S6 = S5 + 1048576;
    if (i < S0) {
        const float4* s = (const float4*)(es + (size_t)i * 8);
        *(bf16x8*)(ES_BF + (size_t)i * 8) = pack8(s[0], s[1]);
    } else if (i < S1) {
        int j = i - S0;
        const float4* s = (const float4*)(U_w + (size_t)j * 8);
        *(bf16x8*)(UW_BF + (size_t)j * 8) = pack8(s[0], s[1]);
    } else if (i < S2) {
        int j = i - S1;
        const float4* s = (const float4*)(W_w + (size_t)j * 8);
        *(bf16x8*)(WW_BF + (size_t)j * 8) = pack8(s[0], s[1]);
    } else if (i < S3) {
        int j = i - S2;
        const float4* s = (const float4*)(fc_w + (size_t)j * 8);
        *(bf16x8*)(FCW_BF + (size_t)j * 8) = pack8(s[0], s[1]);
    } else if (i < S4) {
        int j = i - S3;
        int n = j >> 7, e0 = (j & 127) * 8;
        const float4* p0 = (const float4*)(hidden + (size_t)n * 1024 + e0);
        const float4* p1 = (const float4*)(hidden + 262144 + (size_t)n * 1024 + e0);
        bf16x8 o0 = pack8(p0[0], p0[1]);
        bf16x8 o1 = pack8(p1[0], p1[1]);
        *(bf16x8*)(A0 + (size_t)n * 3328 + 2304 + e0) = o0;
        *(bf16x8*)(A1 + (size_t)n * 2048 + 1024 + e0) = o1;
        *(bf16x8*)(H1B + (size_t)n * 1024 + e0) = o1;
    } else if (i < S5) {
        unsigned j = (unsigned)(i - S4);
        unsigned r = j / 416u;
        int kc = (int)(j - r * 416u) * 8;
        const float* src = nullptr;
        if (r < 2048)      src = (kc < 2304) ? (Wih0 + (size_t)r * 2304 + kc)
                                             : (Whh0 + (size_t)r * 1024 + (kc - 2304));
        else if (r < 3072) { if (kc < 2304)  src = Wih0 + (size_t)r * 2304 + kc; }
        else               { if (kc >= 2304) src = Whh0 + (size_t)(r - 1024) * 1024 + (kc - 2304); }
        bf16x8 o;
        if (src) { const float4* s4 = (const float4*)src; o = pack8(s4[0], s4[1]); }
        else     { for (int k = 0; k < 8; ++k) o[k] = 0; }
        *(bf16x8*)(B0 + (size_t)r * 3328 + kc) = o;
    } else if (i < S6) {
        int j = i - S5;
        int r = j >> 8;
        int kc = (j & 255) * 8;
        const float* src = nullptr;
        if (r < 2048)      src = (kc < 1024) ? (Wih1 + (size_t)r * 1024 + kc)
                                             : (Whh1 + (size_t)r * 1024 + (kc - 1024));
        else if (r < 3072) { if (kc < 1024)  src = Wih1 + (size_t)r * 1024 + kc; }
        else               { if (kc >= 1024) src = Whh1 + (size_t)(r - 1024) * 1024 + (kc - 1024); }
        bf16x8 o;
        if (src) { const float4* s4 = (const float4*)src; o = pack8(s4[0], s4[1]); }
        else     { for (int k = 0; k < 8; ++k) o[k] = 0; }
        *(bf16x8*)(B1 + (size_t)r * 2048 + kc) = o;
    }
}

// ---------------- split-K GEMM: Cpart[z] = A(MxK[slice z]) * B(NxK)^T ----------------
__global__ __launch_bounds__(256) void gemm_bt_sk(
        const unsigned short* __restrict__ A, const unsigned short* __restrict__ B,
        float* __restrict__ Cpart, int N, int K, int ksl) {
    __shared__ unsigned short sA[4096];
    __shared__ unsigned short sB[4096];
    const int nbx = gridDim.x;
    const int nwg = nbx * gridDim.y;
    int d = blockIdx.y * nbx + blockIdx.x;
    int f = d;
    if ((nwg & 7) == 0) { int cpx = nwg >> 3; f = (d & 7) * cpx + (d >> 3); }
    const int bx = f % nbx, by = f / nbx;
    const int z = blockIdx.z;
    const int t = threadIdx.x, wave = t >> 6, lane = t & 63;
    const int wm = wave >> 1, wn = wave & 1;
    const int lg = lane >> 4, r16 = lane & 15;
    const int row0 = by * 128, col0 = bx * 128;
    const int M = gridDim.y * 128;

    const int cr = t >> 2, ckc = (t & 3) * 8;
    const unsigned short* gA  = A + (size_t)(row0 + cr) * K + (size_t)z * ksl + ckc;
    const unsigned short* gA2 = gA + (size_t)64 * K;
    const unsigned short* gB  = B + (size_t)(col0 + cr) * K + (size_t)z * ksl + ckc;
    const unsigned short* gB2 = gB + (size_t)64 * K;
    unsigned short* lA1 = sA + wave * 512;
    unsigned short* lA2 = sA + 2048 + wave * 512;
    unsigned short* lB1 = sB + wave * 512;
    unsigned short* lB2 = sB + 2048 + wave * 512;

    f32x4 acc[4][4];
    #pragma unroll
    for (int i = 0; i < 4; ++i)
        #pragma unroll
        for (int j = 0; j < 4; ++j)
            #pragma unroll
            for (int q = 0; q < 4; ++q) acc[i][j][q] = 0.0f;

    const int ao = (wm * 64 + r16) * 32 + lg * 8;
    const int bo = (wn * 64 + r16) * 32 + lg * 8;

    #pragma unroll 1
    for (int kt = 0; kt < ksl; kt += 32) {
        GLOAD_LDS16(gA, lA1); GLOAD_LDS16(gA2, lA2);
        GLOAD_LDS16(gB, lB1); GLOAD_LDS16(gB2, lB2);
        gA += 32; gA2 += 32; gB += 32; gB2 += 32;
        __syncthreads();
        bf16x8 af[4], bfr[4];
        #pragma unroll
        for (int i = 0; i < 4; ++i) af[i]  = *(const bf16x8*)(sA + ao + i * 512);
        #pragma unroll
        for (int j = 0; j < 4; ++j) bfr[j] = *(const bf16x8*)(sB + bo + j * 512);
        #pragma unroll
        for (int i = 0; i < 4; ++i)
            #pragma unroll
            for (int j = 0; j < 4; ++j)
                acc[i][j] = __builtin_amdgcn_mfma_f32_16x16x32_bf16(af[i], bfr[j], acc[i][j], 0, 0, 0);
        __syncthreads();
    }
    float* Cz = Cpart + (size_t)z * (size_t)M * N;
    #pragma unroll
    for (int i = 0; i < 4; ++i)
        #pragma unroll
        for (int j = 0; j < 4; ++j)
            #pragma unroll
            for (int q = 0; q < 4; ++q) {
                int row = row0 + wm * 64 + i * 16 + lg * 4 + q;
                int col = col0 + wn * 64 + j * 16 + r16;
                Cz[(size_t)row * N + col] = acc[i][j][q];
            }
}

// ---------------- u-GEMM: 128^2 tile, BK=64, 64 KB LDS -> 2 blocks/CU co-resident ----------
// A = es_bf16 (16384 x 2048); B = U_w_bf16 (1024 x 2048). grid (8, 128), 256 thr, 4 waves.
// LDS: 2 slots x (A[128][64] + B[128][64]) bf16 = 64 KiB. Co-resident unsynchronized blocks
// interleave LDS-read and MFMA phases (m114 overlap) — the lever the 8-wave single-block
// family lacked (invariant ~610 TF across R2/R3/R4/R6).
// Pipeline: STAGE(t+1) [8 gload_lds/thread] -> WAITV(8) [tile t landed, t+1 in flight,
// never drains mid-loop] -> barrier -> 16 ds_read_b128 + 32 MFMA (compiler lgkm) -> barrier.
// Swizzle (R3-proven 0-conflict): LDS slot s of row r holds global slot s^(r&7); staged via
// per-lane pre-swizzled source slot (l&7)^(l>>3); read byte (lg*16 ^ ((r16&7)<<4)) ^ (kk<<6).
__global__ __launch_bounds__(256) void gemm_energy128(
        const unsigned short* __restrict__ A, const unsigned short* __restrict__ B,
        const float* __restrict__ attn_w, const float* __restrict__ U_b,
        const float* __restrict__ wbuf, float* __restrict__ e_part) {
    const int NTT = 32;                                 // 2048 / 64 — FULL K (R7 bug fixed)
    __shared__ __align__(16) char lds[65536];           // 2 slots x 32 KiB

    const int t = threadIdx.x;
    const int w = t >> 6, lane = t & 63;
    const int wm = w >> 1, wn = w & 1;
    const int lg = lane >> 4, r16 = lane & 15;

    int d = blockIdx.y * gridDim.x + blockIdx.x;        // 1024 blocks
    int f = (d & 7) * 128 + (d >> 3);                   // bijective XCD swizzle (1024%8==0)
    const int bx = f & 7, by = f >> 3;                  // bx-minor: A-panel L2 reuse per XCD
    const int row0 = by * 128, col0 = bx * 128;

    // staging: 8 chunks/thread (q): q<4 -> A rounds, q>=4 -> B rounds; round rq = 32 rows.
    // lane l: row = rq*32 + w*8 + (l>>3); global 16B-slot (l&7)^(l>>3); LDS dest linear.
    const unsigned short* gsrc[8];
    unsigned lodst[8];
    #pragma unroll
    for (int q = 0; q < 8; ++q) {
        int isB = q >> 2, rq = q & 3;
        int row = rq * 32 + w * 8 + (lane >> 3);
        int slot = (lane & 7) ^ (lane >> 3);
        gsrc[q] = (isB ? B + (size_t)(col0 + row) * 2048
                       : A + (size_t)(row0 + row) * 2048) + slot * 8;
        lodst[q] = (unsigned)(isB * 16384 + (rq * 32 + w * 8) * 128);
    }

#define STAGE(T) do { \
    char* lp_ = lds + ((T) & 1) * 32768; \
    _Pragma("unroll") \
    for (int q_ = 0; q_ < 8; ++q_) \
        GLOAD_LDS16(gsrc[q_] + (size_t)(T) * 64, lp_ + lodst[q_]); \
} while (0)

    const unsigned swz = (unsigned)((r16 & 7) << 4);
    unsigned aoff[4], boff[4];
    #pragma unroll
    for (int m = 0; m < 4; ++m)
        aoff[m] = ((unsigned)((wm * 64 + m * 16 + r16) * 128 + lg * 16)) ^ swz;
    #pragma unroll
    for (int n = 0; n < 4; ++n)
        boff[n] = 16384u + (((unsigned)((wn * 64 + n * 16 + r16) * 128 + lg * 16)) ^ swz);

    f32x4 acc[4][4];
    #pragma unroll
    for (int m = 0; m < 4; ++m)
        #pragma unroll
        for (int n = 0; n < 4; ++n)
            #pragma unroll
            for (int q = 0; q < 4; ++q) acc[m][n][q] = 0.0f;

    STAGE(0);
    #pragma unroll 1
    for (int tt = 0; tt < NTT; ++tt) {
        if (tt + 1 < NTT) { STAGE(tt + 1); WAITV(8); }   // counted: tile tt landed, t+1 flying
        else              { WAITV(0); }
        BARR;
        const char* lp = lds + (tt & 1) * 32768;
        #pragma unroll
        for (int kk = 0; kk < 2; ++kk) {
            bf16x8 afr[4], bfr[4];
            #pragma unroll
            for (int n = 0; n < 4; ++n) bfr[n] = *(const bf16x8*)(lp + (boff[n] ^ (kk << 6)));
            #pragma unroll
            for (int m = 0; m < 4; ++m) afr[m] = *(const bf16x8*)(lp + (aoff[m] ^ (kk << 6)));
            #pragma unroll
            for (int m = 0; m < 4; ++m)
                #pragma unroll
                for (int n = 0; n < 4; ++n)
                    acc[m][n] = __builtin_amdgcn_mfma_f32_16x16x32_bf16(
                        afr[m], bfr[n], acc[m][n], 0, 0, 0);
        }
        BARR;   // all waves done reading slot tt&1 before next iteration stages into it
    }
#undef STAGE

    // fused energy epilogue: e_part[row*16 + bx*2 + wn]
    float aw[4], ub[4];
    #pragma unroll
    for (int n = 0; n < 4; ++n) {
        int col = col0 + wn * 64 + n * 16 + r16;
        aw[n] = attn_w[col];
        ub[n] = U_b[col];
    }
    #pragma unroll
    for (int m = 0; m < 4; ++m)
        #pragma unroll
        for (int q = 0; q < 4; ++q) {
            int row = row0 + wm * 64 + m * 16 + lg * 4 + q;
            const float* wrow = wbuf + (size_t)(row & 255) * 1024;
            float e = 0.f;
            #pragma unroll
            for (int n = 0; n < 4; ++n) {
                int col = col0 + wn * 64 + n * 16 + r16;
                float cc = acc[m][n][q] + ub[n] + wrow[col];
                float ex = __expf(2.f * cc);               // tanh via exp
                e += aw[n] * (1.f - 2.f / (ex + 1.f));
            }
            e += __shfl_xor(e, 1); e += __shfl_xor(e, 2);
            e += __shfl_xor(e, 4); e += __shfl_xor(e, 8);
            if (r16 == 0) e_part[(size_t)row * 16 + bx * 2 + wn] = e;
        }
}

// ---------------- fused softmax + context + emb gather (bf16 es) ----------------
__global__ __launch_bounds__(256) void k_softctx(
        const unsigned short* __restrict__ esb, const float* __restrict__ e_part,
        const float* __restrict__ emb, const int* __restrict__ x,
        float* __restrict__ attn_out, unsigned short* __restrict__ A0) {
    int n = blockIdx.x, t = threadIdx.x;
    __shared__ float as_[64];
    __shared__ float ev[64];
    {   // energy reduce: thread t -> s = t>>2, quarter (t&3)
        int s = t >> 2;
        const float* p = e_part + ((size_t)(s * 256 + n)) * 16 + (t & 3) * 4;
        float v = p[0] + p[1] + p[2] + p[3];
        v += __shfl_xor(v, 1); v += __shfl_xor(v, 2);
        if ((t & 3) == 0) ev[s] = v;
        __syncthreads();
        if (t < 64) {
            float e = ev[t];
            float mx = e;
            #pragma unroll
            for (int o = 1; o < 64; o <<= 1) mx = fmaxf(mx, __shfl_xor(mx, o));
            float ee = __expf(e - mx);
            float sum = ee;
            #pragma unroll
            for (int o = 1; o < 64; o <<= 1) sum += __shfl_xor(sum, o);
            float a = ee / sum;
            as_[t] = a;
            attn_out[t * 256 + n] = a;
        }
        __syncthreads();
    }
    float acc[8];
    #pragma unroll
    for (int k = 0; k < 8; ++k) acc[k] = 0.f;
    const unsigned short* base = esb + (size_t)n * 2048 + t * 8;
    for (int s = 0; s < 64; ++s) {
        bf16x8 v = *(const bf16x8*)(base + (size_t)s * 524288);
        float a = as_[s];
        #pragma unroll
        for (int k = 0; k < 8; ++k) acc[k] += a * bf2f((unsigned short)v[k]);
    }
    bf16x8 o;
    #pragma unroll
    for (int k = 0; k < 8; ++k) o[k] = (short)f2bf(acc[k]);
    *(bf16x8*)(A0 + (size_t)n * 3328 + t * 8) = o;
    if (t < 32) {
        const float4* e4 = (const float4*)(emb + (size_t)x[n] * 256 + t * 8);
        *(bf16x8*)(A0 + (size_t)n * 3328 + 2048 + t * 8) = pack8(e4[0], e4[1]);
    }
}

// GRU gate math; sums 4 split-K partials of g: [Z][256][4096] = [r | z | i_n | h_n]
__global__ void k_gru(const float* __restrict__ g, const float* __restrict__ b_ih,
                      const float* __restrict__ b_hh, const float* __restrict__ h_in,
                      float* __restrict__ h_out, unsigned short* __restrict__ a_dst,
                      int dst_pitch) {
    int i = blockIdx.x * blockDim.x + threadIdx.x;   // 262144
    int n = i >> 10, e = i & 1023;
    const float* gn = g + (size_t)n * 4096;
    float rr = 0.f, zz = 0.f, in_ = 0.f, hn_ = 0.f;
    #pragma unroll
    for (int z = 0; z < 4; ++z) {
        const float* gz = gn + (size_t)z * 1048576;
        rr  += gz[e];
        zz  += gz[1024 + e];
        in_ += gz[2048 + e];
        hn_ += gz[3072 + e];
    }
    rr  += b_ih[e]        + b_hh[e];
    zz  += b_ih[1024 + e] + b_hh[1024 + e];
    in_ += b_ih[2048 + e];
    hn_ += b_hh[2048 + e];
    float r = 1.f / (1.f + __expf(-rr));
    float z = 1.f / (1.f + __expf(-zz));
    float ex = __expf(2.f * (in_ + r * hn_));
    float nn = 1.f - 2.f / (ex + 1.f);
    float h = h_in[i];
    float ho = (1.f - z) * nn + z * h;
    h_out[i] = ho;
    a_dst[(size_t)n * dst_pitch + e] = f2bf(ho);
}

// sum 4 split-K partials + bias (w matrix: 256x1024)
__global__ void k_wsum(const float* __restrict__ Wp, const float* __restrict__ W_b,
                       float* __restrict__ Wout) {
    int i = blockIdx.x * blockDim.x + threadIdx.x;   // 262144
    Wout[i] = Wp[i] + Wp[262144 + i] + Wp[524288 + i] + Wp[786432 + i] + W_b[i & 1023];
}

// sum 4 split-K partials + bias (predictions: 256x128)
__global__ void k_fcsum(const float* __restrict__ Fp, const float* __restrict__ fc_b,
                        float* __restrict__ outp) {
    int i = blockIdx.x * blockDim.x + threadIdx.x;   // 32768
    outp[i] = Fp[i] + Fp[32768 + i] + Fp[65536 + i] + Fp[98304 + i] + fc_b[i & 127];
}

// ---------------- launch ----------------

extern "C" void kernel_launch(void* const* d_in, const int* in_sizes, int n_in,
                              void* d_out, int out_size, void* d_ws, size_t ws_size,
                              hipStream_t stream) {
    const int*   x      = (const int*)  d_in[0];
    const float* es     = (const float*)d_in[1];
    const float* hidden = (const float*)d_in[2];
    const float* emb    = (const float*)d_in[4];
    const float* U_w    = (const float*)d_in[5];
    const float* U_b    = (const float*)d_in[6];
    const float* W_w    = (const float*)d_in[7];
    const float* W_b    = (const float*)d_in[8];
    const float* attn_w = (const float*)d_in[9];
    const float* W_ih0  = (const float*)d_in[11];
    const float* W_hh0  = (const float*)d_in[12];
    const float* b_ih0  = (const float*)d_in[13];
    const float* b_hh0  = (const float*)d_in[14];
    const float* W_ih1  = (const float*)d_in[15];
    const float* W_hh1  = (const float*)d_in[16];
    const float* b_ih1  = (const float*)d_in[17];
    const float* b_hh1  = (const float*)d_in[18];
    const float* fc_w   = (const float*)d_in[19];
    const float* fc_b   = (const float*)d_in[20];

    float* out        = (float*)d_out;
    float* out_pred   = out;
    float* out_hidden = out + 32768;
    float* out_attn   = out + 32768 + 524288;

    char* ws = (char*)d_ws;
    size_t off = 0;
    auto alloc = [&](size_t bytes) { char* p = ws + off; off += (bytes + 255) & ~(size_t)255; return p; };
    unsigned short* ES_BF  = (unsigned short*)alloc((size_t)16384 * 2048 * 2);
    unsigned short* UW_BF  = (unsigned short*)alloc((size_t)1024 * 2048 * 2);
    unsigned short* WW_BF  = (unsigned short*)alloc((size_t)1024 * 1024 * 2);
    unsigned short* FCW_BF = (unsigned short*)alloc((size_t)128 * 1024 * 2);
    unsigned short* H1_BF  = (unsigned short*)alloc((size_t)256 * 1024 * 2);
    unsigned short* B0     = (unsigned short*)alloc((size_t)4096 * 3328 * 2);
    unsigned short* B1     = (unsigned short*)alloc((size_t)4096 * 2048 * 2);
    unsigned short* A0     = (unsigned short*)alloc((size_t)256 * 3328 * 2);
    unsigned short* A1     = (unsigned short*)alloc((size_t)256 * 2048 * 2);
    unsigned short* FCA    = (unsigned short*)alloc((size_t)256 * 1024 * 2);
    float* WBUF  = (float*)alloc((size_t)256 * 1024 * 4);
    float* EPART = (float*)alloc((size_t)16384 * 16 * 4);
    float* WP    = (float*)alloc((size_t)4 * 256 * 1024 * 4);   // w partials; reused for fc partials
    float* G0P   = (float*)alloc((size_t)4 * 256 * 4096 * 4);   // GRU0 partials; reused for GRU1
    float* FCP   = WP;
    float* G1P   = G0P;

    // fused prep
    k_prep<<<28864, 256, 0, stream>>>(es, U_w, W_w, fc_w, hidden, W_ih0, W_hh0, W_ih1, W_hh1,
                                      ES_BF, UW_BF, WW_BF, FCW_BF, A0, A1, H1_BF, B0, B1);
    // w = hidden[1] @ W_w^T + W_b  (split-K 4)
    gemm_bt_sk<<<dim3(8, 2, 4), 256, 0, stream>>>(H1_BF, WW_BF, WP, 1024, 1024, 256);
    k_wsum<<<1024, 256, 0, stream>>>(WP, W_b, WBUF);
    // u-GEMM + fused energy epilogue (128^2, 2 blocks/CU co-resident, full K)
    gemm_energy128<<<dim3(8, 128), 256, 0, stream>>>(ES_BF, UW_BF, attn_w, U_b, WBUF, EPART);
    // softmax + context + embedding -> out_attn, A0
    k_softctx<<<256, 256, 0, stream>>>(ES_BF, EPART, emb, x, out_attn, A0);
    // GRU layer 0 (split-K 4: 3328 = 4*832)
    gemm_bt_sk<<<dim3(32, 2, 4), 256, 0, stream>>>(A0, B0, G0P, 4096, 3328, 832);
    k_gru<<<1024, 256, 0, stream>>>(G0P, b_ih0, b_hh0, hidden, out_hidden, A1, 2048);
    // GRU layer 1 (split-K 4: 2048 = 4*512)
    gemm_bt_sk<<<dim3(32, 2, 4), 256, 0, stream>>>(A1, B1, G1P, 4096, 2048, 512);
    k_gru<<<1024, 256, 0, stream>>>(G1P, b_ih1, b_hh1, hidden + 262144, out_hidden + 262144, FCA, 1024);
    // predictions = h1 @ fc_w^T + fc_b (split-K 4)
    gemm_bt_sk<<<dim3(1, 2, 4), 256, 0, stream>>>(FCA, FCW_BF, FCP, 128, 1024, 256);
    k_fcsum<<<128, 256, 0, stream>>>(FCP, fc_b, out_pred);
}